// Round 11
// baseline (46.542 us; speedup 1.0000x reference)
//
#include <hip/hip_runtime.h>
#include <hip/hip_bf16.h>

// Problem: B=N=1024, in_f=1024, OUT_F=32, KD=8
// out[n][0:1024]   = x[n][:]
// M[n][o*8+k]      = sum_f x[n][f] * T[f][o*8+k]        (T flat [1024][256])
// out[n][1024+o]   = sum_{i != n} exp(-sum_k |M[i][o*8+k] - M[n][o*8+k]|)
//
// R10: 3 nodes: prep (copy/cast/transpose + zero M + zero o_b cols)
//   -> gemm_mfma (K-split, epilogue atomicAdd M += acc*log2e, no part/reduce)
//   -> pairwise8 (Jpt=2, i-split 2, 512 blocks x 256 thr, exp2, atomicAdd out).

#define N_ROWS 1024
#define IN_F   1024
#define OUT_C  1056
#define OK     256   // OUT_F*KD
#define KS     8     // K-split factor
#define KC     128   // K-chunk = IN_F/KS
#define LOG2E  1.44269504f

typedef __attribute__((ext_vector_type(8))) short bf16x8;
typedef __attribute__((ext_vector_type(4))) float f32x4;

__device__ __forceinline__ unsigned short f2bf(float f) {
  unsigned u = __float_as_uint(f);
  u = (u + 0x7FFFu + ((u >> 16) & 1u)) >> 16;   // RNE
  return (unsigned short)u;
}

__device__ __forceinline__ float fast_exp2(float x) {
#if __has_builtin(__builtin_amdgcn_exp2f)
  return __builtin_amdgcn_exp2f(x);   // v_exp_f32 = 2^x
#else
  return __expf(x * 0.6931472f);
#endif
}

// ---------------- kernel 1: prep ---------------------------------------------
// blocks 0-511: copy 2 x-rows -> out, cast -> xb, zero those rows' o_b cols
// blocks 512-575: transpose T -> Tt (bf16) and zero M (16 floats/thread)
__global__ __launch_bounds__(256) void prep_kernel(
    const float* __restrict__ x, const float* __restrict__ T,
    float* __restrict__ out, unsigned short* __restrict__ xb,
    unsigned short* __restrict__ Tt, float* __restrict__ M) {
  const int b = blockIdx.x, t = threadIdx.x;
  if (b < 512) {
#pragma unroll
    for (int u = 0; u < 2; ++u) {
      int idx = b * 512 + u * 256 + t;          // 262144 float4 groups
      int row = idx >> 8, col4 = idx & 255;     // 256 float4 per row; rows 2b,2b+1
      float4 v = *reinterpret_cast<const float4*>(x + (size_t)row * IN_F + col4 * 4);
      *reinterpret_cast<float4*>(out + (size_t)row * OUT_C + col4 * 4) = v;
      ushort4 h = make_ushort4(f2bf(v.x), f2bf(v.y), f2bf(v.z), f2bf(v.w));
      *reinterpret_cast<ushort4*>(xb + (size_t)row * IN_F + col4 * 4) = h;
    }
    if (t < 16) {   // zero o_b cols of rows 2b, 2b+1 (pairwise atomics target)
      int row = b * 2 + (t >> 3), f4 = t & 7;
      *reinterpret_cast<float4*>(out + (size_t)row * OUT_C + 1024 + f4 * 4) =
          make_float4(0.f, 0.f, 0.f, 0.f);
    }
  } else {
    int c = (b - 512) * 4 + (t >> 6);   // 0..255
    int g = t & 63;
#pragma unroll
    for (int u = 0; u < 2; ++u) {
      int k0 = g * 16 + u * 8;
      unsigned short h[8];
#pragma unroll
      for (int j = 0; j < 8; ++j)
        h[j] = f2bf(T[(size_t)(k0 + j) * OK + c]);
      *reinterpret_cast<uint4*>(Tt + (size_t)c * IN_F + k0) =
          *reinterpret_cast<const uint4*>(h);
    }
    // zero M: 16384 threads x 16 floats = 1 MB
    int gid = (b - 512) * 256 + t;
    float4 z = make_float4(0.f, 0.f, 0.f, 0.f);
#pragma unroll
    for (int q = 0; q < 4; ++q)
      *reinterpret_cast<float4*>(M + (size_t)gid * 16 + q * 4) = z;
  }
}

// ---------------- kernel 2: bf16 MFMA GEMM, atomic accumulate into M ---------
// R7 schedule verbatim; epilogue: M += acc * LOG2E via global atomicAdd
// (8 K-slice contenders per address; fp32 order nondet ~1e-10, threshold 0.099).
__global__ __launch_bounds__(256) void gemm_mfma_kernel(
    const unsigned short* __restrict__ xb,  // [1024][1024] bf16
    const unsigned short* __restrict__ Tt,  // [256][1024] bf16 (T transposed)
    float* __restrict__ M) {                // [1024][256], pre-zeroed
  __shared__ unsigned short asw[64 * 128];
  __shared__ unsigned short bsw[64 * 128];
  const int m0 = blockIdx.x * 64;
  const int n0 = blockIdx.y * 64;
  const int ks = blockIdx.z;
  const int t  = threadIdx.x;

#pragma unroll
  for (int u = 0; u < 4; ++u) {
    int idx = t + 256 * u;
    int row = idx >> 4, slot = idx & 15;
    uint4 va = *reinterpret_cast<const uint4*>(
        xb + (size_t)(m0 + row) * IN_F + ks * KC + slot * 8);
    *reinterpret_cast<uint4*>(asw + row * 128 + ((slot ^ (row & 15)) * 8)) = va;
    uint4 vb = *reinterpret_cast<const uint4*>(
        Tt + (size_t)(n0 + row) * IN_F + ks * KC + slot * 8);
    *reinterpret_cast<uint4*>(bsw + row * 128 + ((slot ^ (row & 15)) * 8)) = vb;
  }
  __syncthreads();

  const int l  = t & 63, w = t >> 6;
  const int lr = l & 15, lg = l >> 4;
  f32x4 acc0 = {0.f, 0.f, 0.f, 0.f};
  f32x4 acc1 = {0.f, 0.f, 0.f, 0.f};
  f32x4 acc2 = {0.f, 0.f, 0.f, 0.f};
  f32x4 acc3 = {0.f, 0.f, 0.f, 0.f};

  const int arow = w * 16 + lr;
  const int aswz = arow & 15;
#pragma unroll
  for (int kk = 0; kk < 4; ++kk) {
    int slotA = kk * 4 + lg;
    bf16x8 a = *reinterpret_cast<const bf16x8*>(
        asw + arow * 128 + ((slotA ^ aswz) * 8));
    int sb = (slotA ^ lr) * 8;
    bf16x8 b0 = *reinterpret_cast<const bf16x8*>(bsw + (lr)      * 128 + sb);
    bf16x8 b1 = *reinterpret_cast<const bf16x8*>(bsw + (16 + lr) * 128 + sb);
    bf16x8 b2 = *reinterpret_cast<const bf16x8*>(bsw + (32 + lr) * 128 + sb);
    bf16x8 b3 = *reinterpret_cast<const bf16x8*>(bsw + (48 + lr) * 128 + sb);
    acc0 = __builtin_amdgcn_mfma_f32_16x16x32_bf16(a, b0, acc0, 0, 0, 0);
    acc1 = __builtin_amdgcn_mfma_f32_16x16x32_bf16(a, b1, acc1, 0, 0, 0);
    acc2 = __builtin_amdgcn_mfma_f32_16x16x32_bf16(a, b2, acc2, 0, 0, 0);
    acc3 = __builtin_amdgcn_mfma_f32_16x16x32_bf16(a, b3, acc3, 0, 0, 0);
  }

  // C/D layout: col = lane&15, row = (lane>>4)*4 + reg
  float* dst = M + (size_t)(m0 + w * 16 + lg * 4) * OK + n0 + lr;
#pragma unroll
  for (int r = 0; r < 4; ++r) {
    atomicAdd(&dst[(size_t)r * OK],      acc0[r] * LOG2E);
    atomicAdd(&dst[(size_t)r * OK + 16], acc1[r] * LOG2E);
    atomicAdd(&dst[(size_t)r * OK + 32], acc2[r] * LOG2E);
    atomicAdd(&dst[(size_t)r * OK + 48], acc3[r] * LOG2E);
  }
}

// ---------------- fallback GEMM (small ws): single-pass fp32, M pre-scaled ---
#define BK 16
__global__ __launch_bounds__(256) void gemm32_kernel(
    const float* __restrict__ A, const float* __restrict__ Bm, float* __restrict__ M) {
  __shared__ float as2[BK][32];
  __shared__ float bs2[BK][32];
  int m0 = blockIdx.x * 32;
  int n0 = blockIdx.y * 32;
  int t  = threadIdx.x;
  int ty = t >> 4, tx = t & 15;
  float c00 = 0.f, c01 = 0.f, c10 = 0.f, c11 = 0.f;
  for (int k0 = 0; k0 < IN_F; k0 += BK) {
    if (t < 128) {
      int row = t >> 2, q = t & 3;
      float4 v = *reinterpret_cast<const float4*>(A + (size_t)(m0 + row) * IN_F + k0 + q * 4);
      as2[q * 4 + 0][row] = v.x; as2[q * 4 + 1][row] = v.y;
      as2[q * 4 + 2][row] = v.z; as2[q * 4 + 3][row] = v.w;
    } else {
      int tt = t - 128;
      int row = tt >> 3, q = tt & 7;
      float4 v = *reinterpret_cast<const float4*>(Bm + (size_t)(k0 + row) * OK + n0 + q * 4);
      *reinterpret_cast<float4*>(&bs2[row][q * 4]) = v;
    }
    __syncthreads();
#pragma unroll
    for (int kk = 0; kk < BK; ++kk) {
      float2 a = *reinterpret_cast<const float2*>(&as2[kk][ty * 2]);
      float2 b = *reinterpret_cast<const float2*>(&bs2[kk][tx * 2]);
      c00 += a.x * b.x; c01 += a.x * b.y;
      c10 += a.y * b.x; c11 += a.y * b.y;
    }
    __syncthreads();
  }
  int r = m0 + ty * 2, c = n0 + tx * 2;
  M[(size_t)r * OK + c]           = c00 * LOG2E;
  M[(size_t)r * OK + c + 1]       = c01 * LOG2E;
  M[(size_t)(r + 1) * OK + c]     = c10 * LOG2E;
  M[(size_t)(r + 1) * OK + c + 1] = c11 * LOG2E;
}

// ---------------- kernel 3: pairwise exp2(-L1) v8 ----------------------------
// grid (o:32, jt:8, is:2) = 512 blocks x 256 thr (4 waves) = 2 blocks/CU.
// Stage this block's 512 i-rows (16 KB) + its 128 j-rows (4 KB). Thread owns
// j0 = jt*128+jl, j1 = j0+64 in named regs; wave s walks i in
// [is*512 + s*128, +128): 2 broadcast b128 serve 2 pairs (LDS traffic halved
// vs v2). M is pre-scaled by log2e -> exp2 directly. atomicAdd epilogue
// (2 deterministic contenders; out o_b zeroed in prep).
__global__ __launch_bounds__(256) void pairwise8_kernel(
    const float* __restrict__ M, float* __restrict__ out) {
  __shared__ float smi[512][8];     // 16 KB: i-half rows
  __shared__ float smj[128][8];     // 4 KB: j-window rows
  __shared__ float red[4][130];     // padded wave partials (q*64+jl)

  const int o  = blockIdx.x;   // 0..31
  const int jt = blockIdx.y;   // 0..7
  const int is = blockIdx.z;   // 0..1
  const int t  = threadIdx.x;
  const int jl = t & 63, s = t >> 6;

  const float* Mo = M + o * 8;

  // stage i-half: 512 rows -> 1024 float4, 4/thread, coalesced
#pragma unroll
  for (int u = 0; u < 4; ++u) {
    int idx = t + 256 * u;
    int row = idx >> 1, half = idx & 1;
    *reinterpret_cast<float4*>(&smi[row][half * 4]) =
        *reinterpret_cast<const float4*>(Mo + (size_t)(is * 512 + row) * OK + half * 4);
  }
  // stage j-window: 128 rows -> 256 float4, 1/thread, coalesced
  {
    int row = t >> 1, half = t & 1;
    *reinterpret_cast<float4*>(&smj[row][half * 4]) =
        *reinterpret_cast<const float4*>(Mo + (size_t)(jt * 128 + row) * OK + half * 4);
  }
  __syncthreads();

  float4 ra0 = *reinterpret_cast<const float4*>(&smj[jl][0]);
  float4 rb0 = *reinterpret_cast<const float4*>(&smj[jl][4]);
  float4 ra1 = *reinterpret_cast<const float4*>(&smj[64 + jl][0]);
  float4 rb1 = *reinterpret_cast<const float4*>(&smj[64 + jl][4]);

  float acc0 = 0.f, acc1 = 0.f;
  const float* base = &smi[s * 128][0];
#pragma unroll 4
  for (int ii = 0; ii < 128; ++ii) {
    float4 va = *reinterpret_cast<const float4*>(base + ii * 8);
    float4 vb = *reinterpret_cast<const float4*>(base + ii * 8 + 4);
    float d0 = (fabsf(va.x - ra0.x) + fabsf(va.y - ra0.y)) +
               (fabsf(va.z - ra0.z) + fabsf(va.w - ra0.w)) +
               (fabsf(vb.x - rb0.x) + fabsf(vb.y - rb0.y)) +
               (fabsf(vb.z - rb0.z) + fabsf(vb.w - rb0.w));
    float d1 = (fabsf(va.x - ra1.x) + fabsf(va.y - ra1.y)) +
               (fabsf(va.z - ra1.z) + fabsf(va.w - ra1.w)) +
               (fabsf(vb.x - rb1.x) + fabsf(vb.y - rb1.y)) +
               (fabsf(vb.z - rb1.z) + fabsf(vb.w - rb1.w));
    acc0 += fast_exp2(-d0);   // M pre-scaled by log2e; large d underflows to 0
    acc1 += fast_exp2(-d1);
  }
  // exact self term (exp2(0)=1): i==j occurs in wave s == jt&3 of block is == jt>>2
  if ((jt >> 2) == is && s == (jt & 3)) { acc0 -= 1.f; acc1 -= 1.f; }

  red[s][jl]      = acc0;
  red[s][64 + jl] = acc1;
  __syncthreads();

  if (t < 128) {
    float v = red[0][t] + red[1][t] + red[2][t] + red[3][t];
    int j = jt * 128 + t;
    atomicAdd(&out[(size_t)j * OUT_C + 1024 + o], v);
  }
}

// ---------------- fallback pairwise (v7) + copy ------------------------------
__global__ __launch_bounds__(256) void pairwise_kernel(
    const float* __restrict__ M, float* __restrict__ out) {
  __shared__ float sm[N_ROWS][8];
  __shared__ float red[4][64];

  int o  = blockIdx.x;
  int jt = blockIdx.y;
  int t  = threadIdx.x;

#pragma unroll
  for (int idx = t; idx < 2048; idx += 256) {
    int row = idx >> 1, half = idx & 1;
    *reinterpret_cast<float4*>(&sm[row][half * 4]) =
        *reinterpret_cast<const float4*>(M + (size_t)row * OK + o * 8 + half * 4);
  }
  __syncthreads();

  int jl = t & 63, s = t >> 6;
  int j  = jt * 64 + jl;

  float4 ra = *reinterpret_cast<const float4*>(&sm[j][0]);
  float4 rb = *reinterpret_cast<const float4*>(&sm[j][4]);

  float acc = 0.f;
  const float* base = &sm[s * 256][0];
#pragma unroll 4
  for (int i = 0; i < 256; ++i) {
    float4 va = *reinterpret_cast<const float4*>(base + i * 8);
    float4 vb = *reinterpret_cast<const float4*>(base + i * 8 + 4);
    float d = fabsf(va.x - ra.x) + fabsf(va.y - ra.y) +
              fabsf(va.z - ra.z) + fabsf(va.w - ra.w) +
              fabsf(vb.x - rb.x) + fabsf(vb.y - rb.y) +
              fabsf(vb.z - rb.z) + fabsf(vb.w - rb.w);
    acc += fast_exp2(-d);
  }
  if ((j >> 8) == s) acc -= 1.0f;

  red[s][jl] = acc;
  __syncthreads();

  if (t < 64) {
    float v = red[0][t] + red[1][t] + red[2][t] + red[3][t];
    int jj = jt * 64 + t;
    out[(size_t)jj * OUT_C + 1024 + o] = v;
  }
}

__global__ __launch_bounds__(256) void copy_x_kernel(
    const float* __restrict__ x, float* __restrict__ out) {
  int n = blockIdx.x;
  int c = threadIdx.x * 4;
  float4 v = *reinterpret_cast<const float4*>(x + (size_t)n * IN_F + c);
  *reinterpret_cast<float4*>(out + (size_t)n * OUT_C + c) = v;
}

extern "C" void kernel_launch(void* const* d_in, const int* in_sizes, int n_in,
                              void* d_out, int out_size, void* d_ws, size_t ws_size,
                              hipStream_t stream) {
  const float* x = (const float*)d_in[0];   // [1024][1024]
  const float* T = (const float*)d_in[1];   // [1024][256]
  float* out = (float*)d_out;               // [1024][1056]

  const size_t mElems = (size_t)N_ROWS * OK;           // 262144
  const size_t needed = mElems * 4                     // M     1 MB
                      + (size_t)N_ROWS * IN_F * 2      // xb    2 MB
                      + (size_t)OK * IN_F * 2;         // Tt  0.5 MB

  if (ws_size >= needed) {
    float* M = (float*)d_ws;
    unsigned short* xb = (unsigned short*)(M + mElems);
    unsigned short* Tt = xb + (size_t)N_ROWS * IN_F;

    prep_kernel<<<dim3(576), dim3(256), 0, stream>>>(x, T, out, xb, Tt, M);
    gemm_mfma_kernel<<<dim3(16, 4, KS), dim3(256), 0, stream>>>(xb, Tt, M);
    pairwise8_kernel<<<dim3(32, 8, 2), dim3(256), 0, stream>>>(M, out);
  } else {
    float* M = (float*)d_ws;
    copy_x_kernel<<<dim3(N_ROWS), dim3(256), 0, stream>>>(x, out);
    gemm32_kernel<<<dim3(32, 8), dim3(256), 0, stream>>>(x, T, M);
    pairwise_kernel<<<dim3(32, 16), dim3(256), 0, stream>>>(M, out);
  }
}

// Round 12
// 44.120 us; speedup vs baseline: 1.0549x; 1.0549x over previous
//
#include <hip/hip_runtime.h>
#include <hip/hip_bf16.h>

// Problem: B=N=1024, in_f=1024, OUT_F=32, KD=8
// out[n][0:1024]   = x[n][:]
// M[n][o*8+k]      = sum_f x[n][f] * T[f][o*8+k]        (T flat [1024][256])
// out[n][1024+o]   = sum_{i != n} exp(-sum_k |M[i][o*8+k] - M[n][o*8+k]|)
//
// R11: pipeline = R9 (prep -> gemm_mfma(part) -> reduce -> pairwise).
// reduce folds *log2e into M. pairwise v10 = i-split shape (LDS reads /2)
// + packed-fp32 math (v_pk_add/v_pk_max, VALU /2.5) + raw v_exp_f32.

#define N_ROWS 1024
#define IN_F   1024
#define OUT_C  1056
#define OK     256   // OUT_F*KD
#define KS     8     // K-split factor
#define KC     128   // K-chunk = IN_F/KS
#define LOG2E  1.44269504f

typedef __attribute__((ext_vector_type(8))) short bf16x8;
typedef __attribute__((ext_vector_type(4))) float f32x4;
typedef __attribute__((ext_vector_type(2))) float f32x2;

__device__ __forceinline__ unsigned short f2bf(float f) {
  unsigned u = __float_as_uint(f);
  u = (u + 0x7FFFu + ((u >> 16) & 1u)) >> 16;   // RNE
  return (unsigned short)u;
}

__device__ __forceinline__ float fast_exp2(float x) {
#if __has_builtin(__builtin_amdgcn_exp2f)
  return __builtin_amdgcn_exp2f(x);   // v_exp_f32 = 2^x
#else
  return __expf(x * 0.6931472f);
#endif
}

__device__ __forceinline__ f32x2 pk_abs(f32x2 v) {
  return __builtin_elementwise_max(v, -v);      // v_pk_max_f32 with neg mods
}

// ---------------- kernel 1: prep ---------------------------------------------
// blocks 0-511: copy 2 x-rows -> out, cast -> xb, zero those rows' o_b cols
// blocks 512-575: transpose T -> Tt (bf16)
__global__ __launch_bounds__(256) void prep_kernel(
    const float* __restrict__ x, const float* __restrict__ T,
    float* __restrict__ out, unsigned short* __restrict__ xb,
    unsigned short* __restrict__ Tt) {
  const int b = blockIdx.x, t = threadIdx.x;
  if (b < 512) {
#pragma unroll
    for (int u = 0; u < 2; ++u) {
      int idx = b * 512 + u * 256 + t;          // 262144 float4 groups
      int row = idx >> 8, col4 = idx & 255;     // rows 2b, 2b+1
      float4 v = *reinterpret_cast<const float4*>(x + (size_t)row * IN_F + col4 * 4);
      *reinterpret_cast<float4*>(out + (size_t)row * OUT_C + col4 * 4) = v;
      ushort4 h = make_ushort4(f2bf(v.x), f2bf(v.y), f2bf(v.z), f2bf(v.w));
      *reinterpret_cast<ushort4*>(xb + (size_t)row * IN_F + col4 * 4) = h;
    }
    if (t < 16) {   // zero o_b cols of rows 2b, 2b+1 (pairwise atomic targets)
      int row = b * 2 + (t >> 3), f4 = t & 7;
      *reinterpret_cast<float4*>(out + (size_t)row * OUT_C + 1024 + f4 * 4) =
          make_float4(0.f, 0.f, 0.f, 0.f);
    }
  } else {
    int c = (b - 512) * 4 + (t >> 6);   // 0..255
    int g = t & 63;
#pragma unroll
    for (int u = 0; u < 2; ++u) {
      int k0 = g * 16 + u * 8;
      unsigned short h[8];
#pragma unroll
      for (int j = 0; j < 8; ++j)
        h[j] = f2bf(T[(size_t)(k0 + j) * OK + c]);
      *reinterpret_cast<uint4*>(Tt + (size_t)c * IN_F + k0) =
          *reinterpret_cast<const uint4*>(h);
    }
  }
}

// ---------------- kernel 2: bf16 MFMA GEMM (R7/R9 verbatim) ------------------
__global__ __launch_bounds__(256) void gemm_mfma_kernel(
    const unsigned short* __restrict__ xb,  // [1024][1024] bf16
    const unsigned short* __restrict__ Tt,  // [256][1024] bf16 (T transposed)
    float* __restrict__ part) {             // [KS][1024][256]
  __shared__ unsigned short asw[64 * 128];
  __shared__ unsigned short bsw[64 * 128];
  const int m0 = blockIdx.x * 64;
  const int n0 = blockIdx.y * 64;
  const int ks = blockIdx.z;
  const int t  = threadIdx.x;

#pragma unroll
  for (int u = 0; u < 4; ++u) {
    int idx = t + 256 * u;
    int row = idx >> 4, slot = idx & 15;
    uint4 va = *reinterpret_cast<const uint4*>(
        xb + (size_t)(m0 + row) * IN_F + ks * KC + slot * 8);
    *reinterpret_cast<uint4*>(asw + row * 128 + ((slot ^ (row & 15)) * 8)) = va;
    uint4 vb = *reinterpret_cast<const uint4*>(
        Tt + (size_t)(n0 + row) * IN_F + ks * KC + slot * 8);
    *reinterpret_cast<uint4*>(bsw + row * 128 + ((slot ^ (row & 15)) * 8)) = vb;
  }
  __syncthreads();

  const int l  = t & 63, w = t >> 6;
  const int lr = l & 15, lg = l >> 4;
  f32x4 acc0 = {0.f, 0.f, 0.f, 0.f};
  f32x4 acc1 = {0.f, 0.f, 0.f, 0.f};
  f32x4 acc2 = {0.f, 0.f, 0.f, 0.f};
  f32x4 acc3 = {0.f, 0.f, 0.f, 0.f};

  const int arow = w * 16 + lr;
  const int aswz = arow & 15;
#pragma unroll
  for (int kk = 0; kk < 4; ++kk) {
    int slotA = kk * 4 + lg;
    bf16x8 a = *reinterpret_cast<const bf16x8*>(
        asw + arow * 128 + ((slotA ^ aswz) * 8));
    int sb = (slotA ^ lr) * 8;
    bf16x8 b0 = *reinterpret_cast<const bf16x8*>(bsw + (lr)      * 128 + sb);
    bf16x8 b1 = *reinterpret_cast<const bf16x8*>(bsw + (16 + lr) * 128 + sb);
    bf16x8 b2 = *reinterpret_cast<const bf16x8*>(bsw + (32 + lr) * 128 + sb);
    bf16x8 b3 = *reinterpret_cast<const bf16x8*>(bsw + (48 + lr) * 128 + sb);
    acc0 = __builtin_amdgcn_mfma_f32_16x16x32_bf16(a, b0, acc0, 0, 0, 0);
    acc1 = __builtin_amdgcn_mfma_f32_16x16x32_bf16(a, b1, acc1, 0, 0, 0);
    acc2 = __builtin_amdgcn_mfma_f32_16x16x32_bf16(a, b2, acc2, 0, 0, 0);
    acc3 = __builtin_amdgcn_mfma_f32_16x16x32_bf16(a, b3, acc3, 0, 0, 0);
  }

  float* dst = part + (size_t)ks * (N_ROWS * OK)
             + (size_t)(m0 + w * 16 + lg * 4) * OK + n0 + lr;
#pragma unroll
  for (int r = 0; r < 4; ++r) {
    dst[(size_t)r * OK]      = acc0[r];
    dst[(size_t)r * OK + 16] = acc1[r];
    dst[(size_t)r * OK + 32] = acc2[r];
    dst[(size_t)r * OK + 48] = acc3[r];
  }
}

// ---------------- kernel 3: reduce K-split partials, fold in log2e -----------
__global__ __launch_bounds__(256) void reduce_kernel(
    const float* __restrict__ part, float* __restrict__ M) {
  int g = blockIdx.x * 256 + threadIdx.x;
  const float4* p = reinterpret_cast<const float4*>(part);
  float4 s = p[g];
#pragma unroll
  for (int sl = 1; sl < KS; ++sl) {
    float4 v = p[g + (size_t)sl * (N_ROWS * OK / 4)];
    s.x += v.x; s.y += v.y; s.z += v.z; s.w += v.w;
  }
  s.x *= LOG2E; s.y *= LOG2E; s.z *= LOG2E; s.w *= LOG2E;
  reinterpret_cast<float4*>(M)[g] = s;
}

// ---------------- fallback GEMM (small ws): single-pass fp32, scaled ---------
#define BK 16
__global__ __launch_bounds__(256) void gemm32_kernel(
    const float* __restrict__ A, const float* __restrict__ Bm, float* __restrict__ M) {
  __shared__ float as2[BK][32];
  __shared__ float bs2[BK][32];
  int m0 = blockIdx.x * 32;
  int n0 = blockIdx.y * 32;
  int t  = threadIdx.x;
  int ty = t >> 4, tx = t & 15;
  float c00 = 0.f, c01 = 0.f, c10 = 0.f, c11 = 0.f;
  for (int k0 = 0; k0 < IN_F; k0 += BK) {
    if (t < 128) {
      int row = t >> 2, q = t & 3;
      float4 v = *reinterpret_cast<const float4*>(A + (size_t)(m0 + row) * IN_F + k0 + q * 4);
      as2[q * 4 + 0][row] = v.x; as2[q * 4 + 1][row] = v.y;
      as2[q * 4 + 2][row] = v.z; as2[q * 4 + 3][row] = v.w;
    } else {
      int tt = t - 128;
      int row = tt >> 3, q = tt & 7;
      float4 v = *reinterpret_cast<const float4*>(Bm + (size_t)(k0 + row) * OK + n0 + q * 4);
      *reinterpret_cast<float4*>(&bs2[row][q * 4]) = v;
    }
    __syncthreads();
#pragma unroll
    for (int kk = 0; kk < BK; ++kk) {
      float2 a = *reinterpret_cast<const float2*>(&as2[kk][ty * 2]);
      float2 b = *reinterpret_cast<const float2*>(&bs2[kk][tx * 2]);
      c00 += a.x * b.x; c01 += a.x * b.y;
      c10 += a.y * b.x; c11 += a.y * b.y;
    }
    __syncthreads();
  }
  int r = m0 + ty * 2, c = n0 + tx * 2;
  M[(size_t)r * OK + c]           = c00 * LOG2E;
  M[(size_t)r * OK + c + 1]       = c01 * LOG2E;
  M[(size_t)(r + 1) * OK + c]     = c10 * LOG2E;
  M[(size_t)(r + 1) * OK + c + 1] = c11 * LOG2E;
}

// ---------------- kernel 4: pairwise exp2(-L1) v10 ---------------------------
// grid (o:32, jt:8, is:2) = 512 blocks x 256 thr (4 waves) = 2 blocks/CU.
// Stage i-half (512 rows, 16 KB) + j-window (128 rows, 4 KB). Thread owns
// j0 = jt*128+jl, j1 = j0+64 (named regs). Wave s walks 128 i's: LDS b128
// total = 524k (half of v7). Inner math in packed fp32 (f32x2): pk_sub,
// pk_abs(max,-x), pk-add tree -> ~14 VALU/pair. M pre-scaled -> raw v_exp.
// Epilogue: atomicAdd, exactly 2 commutative contenders -> deterministic.
__global__ __launch_bounds__(256) void pairwise10_kernel(
    const float* __restrict__ M, float* __restrict__ out) {
  __shared__ float smi[512][8];     // 16 KB: i-half rows
  __shared__ float smj[128][8];     // 4 KB: j-window rows
  __shared__ float red[4][130];     // padded wave partials

  const int o  = blockIdx.x;   // 0..31
  const int jt = blockIdx.y;   // 0..7
  const int is = blockIdx.z;   // 0..1
  const int t  = threadIdx.x;
  const int jl = t & 63, s = t >> 6;

  const float* Mo = M + o * 8;

  // stage i-half: 1024 float4, 4/thread
#pragma unroll
  for (int u = 0; u < 4; ++u) {
    int idx = t + 256 * u;
    int row = idx >> 1, half = idx & 1;
    *reinterpret_cast<float4*>(&smi[row][half * 4]) =
        *reinterpret_cast<const float4*>(Mo + (size_t)(is * 512 + row) * OK + half * 4);
  }
  // stage j-window: 256 float4, 1/thread
  {
    int row = t >> 1, half = t & 1;
    *reinterpret_cast<float4*>(&smj[row][half * 4]) =
        *reinterpret_cast<const float4*>(Mo + (size_t)(jt * 128 + row) * OK + half * 4);
  }
  __syncthreads();

  const f32x2* j0p = reinterpret_cast<const f32x2*>(&smj[jl][0]);
  const f32x2* j1p = reinterpret_cast<const f32x2*>(&smj[64 + jl][0]);
  f32x2 r00 = j0p[0], r01 = j0p[1], r02 = j0p[2], r03 = j0p[3];
  f32x2 r10 = j1p[0], r11 = j1p[1], r12 = j1p[2], r13 = j1p[3];

  float acc0 = 0.f, acc1 = 0.f;
  const f32x2* base = reinterpret_cast<const f32x2*>(&smi[s * 128][0]);
#pragma unroll 4
  for (int ii = 0; ii < 128; ++ii) {
    f32x2 v0 = base[ii * 4], v1 = base[ii * 4 + 1];
    f32x2 v2 = base[ii * 4 + 2], v3 = base[ii * 4 + 3];

    f32x2 w0 = pk_abs(v0 - r00) + pk_abs(v1 - r01);
    f32x2 w1 = pk_abs(v2 - r02) + pk_abs(v3 - r03);
    f32x2 wd0 = w0 + w1;
    float d0 = wd0.x + wd0.y;

    f32x2 u0 = pk_abs(v0 - r10) + pk_abs(v1 - r11);
    f32x2 u1 = pk_abs(v2 - r12) + pk_abs(v3 - r13);
    f32x2 ud = u0 + u1;
    float d1 = ud.x + ud.y;

    acc0 += fast_exp2(-d0);   // large d underflows to 0
    acc1 += fast_exp2(-d1);
  }
  // exact self term (exp2(0)=1): j0,j1 live in global i-block jt == is*4+s
  if (is * 4 + s == jt) { acc0 -= 1.f; acc1 -= 1.f; }

  red[s][jl]      = acc0;
  red[s][64 + jl] = acc1;
  __syncthreads();

  if (t < 128) {
    float v = red[0][t] + red[1][t] + red[2][t] + red[3][t];
    int j = jt * 128 + t;
    atomicAdd(&out[(size_t)j * OUT_C + 1024 + o], v);   // 2 contenders, commutative
  }
}

// ---------------- fallback pairwise (v7, exp2) + copy ------------------------
__global__ __launch_bounds__(256) void pairwise_kernel(
    const float* __restrict__ M, float* __restrict__ out) {
  __shared__ float sm[N_ROWS][8];
  __shared__ float red[4][64];

  int o  = blockIdx.x;
  int jt = blockIdx.y;
  int t  = threadIdx.x;

#pragma unroll
  for (int idx = t; idx < 2048; idx += 256) {
    int row = idx >> 1, half = idx & 1;
    *reinterpret_cast<float4*>(&sm[row][half * 4]) =
        *reinterpret_cast<const float4*>(M + (size_t)row * OK + o * 8 + half * 4);
  }
  __syncthreads();

  int jl = t & 63, s = t >> 6;
  int j  = jt * 64 + jl;

  float4 ra = *reinterpret_cast<const float4*>(&sm[j][0]);
  float4 rb = *reinterpret_cast<const float4*>(&sm[j][4]);

  float acc = 0.f;
  const float* base = &sm[s * 256][0];
#pragma unroll 4
  for (int i = 0; i < 256; ++i) {
    float4 va = *reinterpret_cast<const float4*>(base + i * 8);
    float4 vb = *reinterpret_cast<const float4*>(base + i * 8 + 4);
    float d = fabsf(va.x - ra.x) + fabsf(va.y - ra.y) +
              fabsf(va.z - ra.z) + fabsf(va.w - ra.w) +
              fabsf(vb.x - rb.x) + fabsf(vb.y - rb.y) +
              fabsf(vb.z - rb.z) + fabsf(vb.w - rb.w);
    acc += fast_exp2(-d);
  }
  if ((j >> 8) == s) acc -= 1.0f;

  red[s][jl] = acc;
  __syncthreads();

  if (t < 64) {
    float v = red[0][t] + red[1][t] + red[2][t] + red[3][t];
    int jj = jt * 64 + t;
    out[(size_t)jj * OUT_C + 1024 + o] = v;
  }
}

__global__ __launch_bounds__(256) void copy_x_kernel(
    const float* __restrict__ x, float* __restrict__ out) {
  int n = blockIdx.x;
  int c = threadIdx.x * 4;
  float4 v = *reinterpret_cast<const float4*>(x + (size_t)n * IN_F + c);
  *reinterpret_cast<float4*>(out + (size_t)n * OUT_C + c) = v;
}

extern "C" void kernel_launch(void* const* d_in, const int* in_sizes, int n_in,
                              void* d_out, int out_size, void* d_ws, size_t ws_size,
                              hipStream_t stream) {
  const float* x = (const float*)d_in[0];   // [1024][1024]
  const float* T = (const float*)d_in[1];   // [1024][256]
  float* out = (float*)d_out;               // [1024][1056]

  const size_t mElems = (size_t)N_ROWS * OK;           // 262144
  const size_t needed = KS * mElems * 4                // part  8 MB
                      + mElems * 4                     // M     1 MB
                      + (size_t)N_ROWS * IN_F * 2      // xb    2 MB
                      + (size_t)OK * IN_F * 2;         // Tt  0.5 MB

  if (ws_size >= needed) {
    float* part = (float*)d_ws;
    float* M    = part + KS * mElems;
    unsigned short* xb = (unsigned short*)(M + mElems);
    unsigned short* Tt = xb + (size_t)N_ROWS * IN_F;

    prep_kernel<<<dim3(576), dim3(256), 0, stream>>>(x, T, out, xb, Tt);
    gemm_mfma_kernel<<<dim3(16, 4, KS), dim3(256), 0, stream>>>(xb, Tt, part);
    reduce_kernel<<<dim3(256), dim3(256), 0, stream>>>(part, M);
    pairwise10_kernel<<<dim3(32, 8, 2), dim3(256), 0, stream>>>(M, out);
  } else {
    float* M = (float*)d_ws;
    copy_x_kernel<<<dim3(N_ROWS), dim3(256), 0, stream>>>(x, out);
    gemm32_kernel<<<dim3(32, 8), dim3(256), 0, stream>>>(x, T, M);
    pairwise_kernel<<<dim3(32, 16), dim3(256), 0, stream>>>(M, out);
  }
}

// Round 13
// 42.515 us; speedup vs baseline: 1.0947x; 1.0377x over previous
//
#include <hip/hip_runtime.h>
#include <hip/hip_bf16.h>
#include <hip/hip_fp16.h>

// Problem: B=N=1024, in_f=1024, OUT_F=32, KD=8
// out[n][0:1024]   = x[n][:]
// M[n][o*8+k]      = sum_f x[n][f] * T[f][o*8+k]        (T flat [1024][256])
// out[n][1024+o]   = sum_{i != n} exp(-sum_k |M[i][o*8+k] - M[n][o*8+k]|)
//
// R12: prep -> gemm_mfma(part) -> reduce (+log2e, -> f16 Mh) -> pairwise v11.
// v11 = v7 shape verbatim; datapath in packed f16 (__half2): 1 ds_read_b128
// per i-row (was 2) and 11 pk-ops for the abs-diff tree (was ~19 scalar).

#define N_ROWS 1024
#define IN_F   1024
#define OUT_C  1056
#define OK     256   // OUT_F*KD
#define KS     8     // K-split factor
#define KC     128   // K-chunk = IN_F/KS
#define LOG2E  1.44269504f

typedef __attribute__((ext_vector_type(8))) short bf16x8;
typedef __attribute__((ext_vector_type(4))) float f32x4;

__device__ __forceinline__ unsigned short f2bf(float f) {
  unsigned u = __float_as_uint(f);
  u = (u + 0x7FFFu + ((u >> 16) & 1u)) >> 16;   // RNE
  return (unsigned short)u;
}

__device__ __forceinline__ float fast_exp2(float x) {
#if __has_builtin(__builtin_amdgcn_exp2f)
  return __builtin_amdgcn_exp2f(x);   // v_exp_f32 = 2^x
#else
  return __expf(x * 0.6931472f);
#endif
}

// ---------------- kernel 1: prep (R11 verbatim) ------------------------------
// blocks 0-511: copy 2 x-rows -> out, cast -> xb
// blocks 512-575: transpose T -> Tt (bf16)
__global__ __launch_bounds__(256) void prep_kernel(
    const float* __restrict__ x, const float* __restrict__ T,
    float* __restrict__ out, unsigned short* __restrict__ xb,
    unsigned short* __restrict__ Tt) {
  const int b = blockIdx.x, t = threadIdx.x;
  if (b < 512) {
#pragma unroll
    for (int u = 0; u < 2; ++u) {
      int idx = b * 512 + u * 256 + t;          // 262144 float4 groups
      int row = idx >> 8, col4 = idx & 255;     // rows 2b, 2b+1
      float4 v = *reinterpret_cast<const float4*>(x + (size_t)row * IN_F + col4 * 4);
      *reinterpret_cast<float4*>(out + (size_t)row * OUT_C + col4 * 4) = v;
      ushort4 h = make_ushort4(f2bf(v.x), f2bf(v.y), f2bf(v.z), f2bf(v.w));
      *reinterpret_cast<ushort4*>(xb + (size_t)row * IN_F + col4 * 4) = h;
    }
  } else {
    int c = (b - 512) * 4 + (t >> 6);   // 0..255
    int g = t & 63;
#pragma unroll
    for (int u = 0; u < 2; ++u) {
      int k0 = g * 16 + u * 8;
      unsigned short h[8];
#pragma unroll
      for (int j = 0; j < 8; ++j)
        h[j] = f2bf(T[(size_t)(k0 + j) * OK + c]);
      *reinterpret_cast<uint4*>(Tt + (size_t)c * IN_F + k0) =
          *reinterpret_cast<const uint4*>(h);
    }
  }
}

// ---------------- kernel 2: bf16 MFMA GEMM (R7/R9 verbatim) ------------------
__global__ __launch_bounds__(256) void gemm_mfma_kernel(
    const unsigned short* __restrict__ xb,  // [1024][1024] bf16
    const unsigned short* __restrict__ Tt,  // [256][1024] bf16 (T transposed)
    float* __restrict__ part) {             // [KS][1024][256]
  __shared__ unsigned short asw[64 * 128];
  __shared__ unsigned short bsw[64 * 128];
  const int m0 = blockIdx.x * 64;
  const int n0 = blockIdx.y * 64;
  const int ks = blockIdx.z;
  const int t  = threadIdx.x;

#pragma unroll
  for (int u = 0; u < 4; ++u) {
    int idx = t + 256 * u;
    int row = idx >> 4, slot = idx & 15;
    uint4 va = *reinterpret_cast<const uint4*>(
        xb + (size_t)(m0 + row) * IN_F + ks * KC + slot * 8);
    *reinterpret_cast<uint4*>(asw + row * 128 + ((slot ^ (row & 15)) * 8)) = va;
    uint4 vb = *reinterpret_cast<const uint4*>(
        Tt + (size_t)(n0 + row) * IN_F + ks * KC + slot * 8);
    *reinterpret_cast<uint4*>(bsw + row * 128 + ((slot ^ (row & 15)) * 8)) = vb;
  }
  __syncthreads();

  const int l  = t & 63, w = t >> 6;
  const int lr = l & 15, lg = l >> 4;
  f32x4 acc0 = {0.f, 0.f, 0.f, 0.f};
  f32x4 acc1 = {0.f, 0.f, 0.f, 0.f};
  f32x4 acc2 = {0.f, 0.f, 0.f, 0.f};
  f32x4 acc3 = {0.f, 0.f, 0.f, 0.f};

  const int arow = w * 16 + lr;
  const int aswz = arow & 15;
#pragma unroll
  for (int kk = 0; kk < 4; ++kk) {
    int slotA = kk * 4 + lg;
    bf16x8 a = *reinterpret_cast<const bf16x8*>(
        asw + arow * 128 + ((slotA ^ aswz) * 8));
    int sb = (slotA ^ lr) * 8;
    bf16x8 b0 = *reinterpret_cast<const bf16x8*>(bsw + (lr)      * 128 + sb);
    bf16x8 b1 = *reinterpret_cast<const bf16x8*>(bsw + (16 + lr) * 128 + sb);
    bf16x8 b2 = *reinterpret_cast<const bf16x8*>(bsw + (32 + lr) * 128 + sb);
    bf16x8 b3 = *reinterpret_cast<const bf16x8*>(bsw + (48 + lr) * 128 + sb);
    acc0 = __builtin_amdgcn_mfma_f32_16x16x32_bf16(a, b0, acc0, 0, 0, 0);
    acc1 = __builtin_amdgcn_mfma_f32_16x16x32_bf16(a, b1, acc1, 0, 0, 0);
    acc2 = __builtin_amdgcn_mfma_f32_16x16x32_bf16(a, b2, acc2, 0, 0, 0);
    acc3 = __builtin_amdgcn_mfma_f32_16x16x32_bf16(a, b3, acc3, 0, 0, 0);
  }

  float* dst = part + (size_t)ks * (N_ROWS * OK)
             + (size_t)(m0 + w * 16 + lg * 4) * OK + n0 + lr;
#pragma unroll
  for (int r = 0; r < 4; ++r) {
    dst[(size_t)r * OK]      = acc0[r];
    dst[(size_t)r * OK + 16] = acc1[r];
    dst[(size_t)r * OK + 32] = acc2[r];
    dst[(size_t)r * OK + 48] = acc3[r];
  }
}

// ---------------- kernel 3: reduce partials, *log2e, -> f16 Mh ---------------
__global__ __launch_bounds__(256) void reduce_kernel(
    const float* __restrict__ part, __half* __restrict__ Mh) {
  int g = blockIdx.x * 256 + threadIdx.x;    // 65536 groups of 4
  const float4* p = reinterpret_cast<const float4*>(part);
  float4 s = p[g];
#pragma unroll
  for (int sl = 1; sl < KS; ++sl) {
    float4 v = p[g + (size_t)sl * (N_ROWS * OK / 4)];
    s.x += v.x; s.y += v.y; s.z += v.z; s.w += v.w;
  }
  __half2 h01 = __floats2half2_rn(s.x * LOG2E, s.y * LOG2E);
  __half2 h23 = __floats2half2_rn(s.z * LOG2E, s.w * LOG2E);
  reinterpret_cast<__half2*>(Mh)[(size_t)g * 2]     = h01;
  reinterpret_cast<__half2*>(Mh)[(size_t)g * 2 + 1] = h23;
}

// ---------------- fallback GEMM (small ws): single-pass fp32, scaled ---------
#define BK 16
__global__ __launch_bounds__(256) void gemm32_kernel(
    const float* __restrict__ A, const float* __restrict__ Bm, float* __restrict__ M) {
  __shared__ float as2[BK][32];
  __shared__ float bs2[BK][32];
  int m0 = blockIdx.x * 32;
  int n0 = blockIdx.y * 32;
  int t  = threadIdx.x;
  int ty = t >> 4, tx = t & 15;
  float c00 = 0.f, c01 = 0.f, c10 = 0.f, c11 = 0.f;
  for (int k0 = 0; k0 < IN_F; k0 += BK) {
    if (t < 128) {
      int row = t >> 2, q = t & 3;
      float4 v = *reinterpret_cast<const float4*>(A + (size_t)(m0 + row) * IN_F + k0 + q * 4);
      as2[q * 4 + 0][row] = v.x; as2[q * 4 + 1][row] = v.y;
      as2[q * 4 + 2][row] = v.z; as2[q * 4 + 3][row] = v.w;
    } else {
      int tt = t - 128;
      int row = tt >> 3, q = tt & 7;
      float4 v = *reinterpret_cast<const float4*>(Bm + (size_t)(k0 + row) * OK + n0 + q * 4);
      *reinterpret_cast<float4*>(&bs2[row][q * 4]) = v;
    }
    __syncthreads();
#pragma unroll
    for (int kk = 0; kk < BK; ++kk) {
      float2 a = *reinterpret_cast<const float2*>(&as2[kk][ty * 2]);
      float2 b = *reinterpret_cast<const float2*>(&bs2[kk][tx * 2]);
      c00 += a.x * b.x; c01 += a.x * b.y;
      c10 += a.y * b.x; c11 += a.y * b.y;
    }
    __syncthreads();
  }
  int r = m0 + ty * 2, c = n0 + tx * 2;
  M[(size_t)r * OK + c]           = c00 * LOG2E;
  M[(size_t)r * OK + c + 1]       = c01 * LOG2E;
  M[(size_t)(r + 1) * OK + c]     = c10 * LOG2E;
  M[(size_t)(r + 1) * OK + c + 1] = c11 * LOG2E;
}

// ---------------- kernel 4: pairwise exp2(-L1) v11, packed f16 ---------------
// v7 shape verbatim: grid (o:32, jt:16) = 512 blocks x 256 thr (2 blocks/CU),
// stage ALL 1024 i-rows (now 16 KB f16). Per i: ONE ds_read_b128 (8 halves),
// abs-diff tree in __half2 (4 hsub2 + 4 habs2/v_and + 3 hadd2), lo+hi, v_exp.
// Mh pre-scaled by log2e. Self-diff is exactly 0 in f16 -> exact -1.
__global__ __launch_bounds__(256) void pairwise11_kernel(
    const __half* __restrict__ Mh, float* __restrict__ out) {
  __shared__ __half sm[N_ROWS][8];   // 16 KB: Mh[:, o, :]
  __shared__ float red[4][64];

  int o  = blockIdx.x;
  int jt = blockIdx.y;
  int t  = threadIdx.x;

  // stage: 1024 rows x 16B = 1024 uint4, 4/thread, coalesced
#pragma unroll
  for (int idx = t; idx < 1024; idx += 256) {
    *reinterpret_cast<uint4*>(&sm[idx][0]) =
        *reinterpret_cast<const uint4*>(Mh + (size_t)idx * OK + o * 8);
  }
  __syncthreads();

  int jl = t & 63, s = t >> 6;
  int j  = jt * 64 + jl;

  const __half2* jp = reinterpret_cast<const __half2*>(&sm[j][0]);
  __half2 r0 = jp[0], r1 = jp[1], r2 = jp[2], r3 = jp[3];

  float acc = 0.f;
  const __half2* base = reinterpret_cast<const __half2*>(&sm[s * 256][0]);
#pragma unroll 4
  for (int i = 0; i < 256; ++i) {
    __half2 v0 = base[i * 4],     v1 = base[i * 4 + 1];
    __half2 v2 = base[i * 4 + 2], v3 = base[i * 4 + 3];
    __half2 d2 = __hadd2(
        __hadd2(__habs2(__hsub2(v0, r0)), __habs2(__hsub2(v1, r1))),
        __hadd2(__habs2(__hsub2(v2, r2)), __habs2(__hsub2(v3, r3))));
    float d = __low2float(d2) + __high2float(d2);
    acc += fast_exp2(-d);   // large d underflows to 0
  }
  if ((j >> 8) == s) acc -= 1.0f;   // exact self term exp2(0)=1

  red[s][jl] = acc;
  __syncthreads();

  if (t < 64) {
    float v = red[0][t] + red[1][t] + red[2][t] + red[3][t];
    int jj = jt * 64 + t;
    out[(size_t)jj * OUT_C + 1024 + o] = v;
  }
}

// ---------------- fallback pairwise (f32 M, exp2) + copy ---------------------
__global__ __launch_bounds__(256) void pairwise_kernel(
    const float* __restrict__ M, float* __restrict__ out) {
  __shared__ float sm[N_ROWS][8];
  __shared__ float red[4][64];

  int o  = blockIdx.x;
  int jt = blockIdx.y;
  int t  = threadIdx.x;

#pragma unroll
  for (int idx = t; idx < 2048; idx += 256) {
    int row = idx >> 1, half = idx & 1;
    *reinterpret_cast<float4*>(&sm[row][half * 4]) =
        *reinterpret_cast<const float4*>(M + (size_t)row * OK + o * 8 + half * 4);
  }
  __syncthreads();

  int jl = t & 63, s = t >> 6;
  int j  = jt * 64 + jl;

  float4 ra = *reinterpret_cast<const float4*>(&sm[j][0]);
  float4 rb = *reinterpret_cast<const float4*>(&sm[j][4]);

  float acc = 0.f;
  const float* base = &sm[s * 256][0];
#pragma unroll 4
  for (int i = 0; i < 256; ++i) {
    float4 va = *reinterpret_cast<const float4*>(base + i * 8);
    float4 vb = *reinterpret_cast<const float4*>(base + i * 8 + 4);
    float d = fabsf(va.x - ra.x) + fabsf(va.y - ra.y) +
              fabsf(va.z - ra.z) + fabsf(va.w - ra.w) +
              fabsf(vb.x - rb.x) + fabsf(vb.y - rb.y) +
              fabsf(vb.z - rb.z) + fabsf(vb.w - rb.w);
    acc += fast_exp2(-d);
  }
  if ((j >> 8) == s) acc -= 1.0f;

  red[s][jl] = acc;
  __syncthreads();

  if (t < 64) {
    float v = red[0][t] + red[1][t] + red[2][t] + red[3][t];
    int jj = jt * 64 + t;
    out[(size_t)jj * OUT_C + 1024 + o] = v;
  }
}

__global__ __launch_bounds__(256) void copy_x_kernel(
    const float* __restrict__ x, float* __restrict__ out) {
  int n = blockIdx.x;
  int c = threadIdx.x * 4;
  float4 v = *reinterpret_cast<const float4*>(x + (size_t)n * IN_F + c);
  *reinterpret_cast<float4*>(out + (size_t)n * OUT_C + c) = v;
}

extern "C" void kernel_launch(void* const* d_in, const int* in_sizes, int n_in,
                              void* d_out, int out_size, void* d_ws, size_t ws_size,
                              hipStream_t stream) {
  const float* x = (const float*)d_in[0];   // [1024][1024]
  const float* T = (const float*)d_in[1];   // [1024][256]
  float* out = (float*)d_out;               // [1024][1056]

  const size_t mElems = (size_t)N_ROWS * OK;           // 262144
  const size_t needed = KS * mElems * 4                // part  8 MB
                      + mElems * 2                     // Mh  0.5 MB
                      + (size_t)N_ROWS * IN_F * 2      // xb    2 MB
                      + (size_t)OK * IN_F * 2;         // Tt  0.5 MB

  if (ws_size >= needed) {
    float* part = (float*)d_ws;
    __half* Mh  = (__half*)(part + KS * mElems);
    unsigned short* xb = (unsigned short*)(Mh + mElems);
    unsigned short* Tt = xb + (size_t)N_ROWS * IN_F;

    prep_kernel<<<dim3(576), dim3(256), 0, stream>>>(x, T, out, xb, Tt);
    gemm_mfma_kernel<<<dim3(16, 4, KS), dim3(256), 0, stream>>>(xb, Tt, part);
    reduce_kernel<<<dim3(256), dim3(256), 0, stream>>>(part, Mh);
    pairwise11_kernel<<<dim3(32, 16), dim3(256), 0, stream>>>(Mh, out);
  } else {
    float* M = (float*)d_ws;
    copy_x_kernel<<<dim3(N_ROWS), dim3(256), 0, stream>>>(x, out);
    gemm32_kernel<<<dim3(32, 8), dim3(256), 0, stream>>>(x, T, M);
    pairwise_kernel<<<dim3(32, 16), dim3(256), 0, stream>>>(M, out);
  }
}

// Round 14
// 40.188 us; speedup vs baseline: 1.1581x; 1.0579x over previous
//
#include <hip/hip_runtime.h>
#include <hip/hip_bf16.h>
#include <hip/hip_fp16.h>

// Problem: B=N=1024, in_f=1024, OUT_F=32, KD=8
// out[n][0:1024]   = x[n][:]
// M[n][o*8+k]      = sum_f x[n][f] * T[f][o*8+k]        (T flat [1024][256])
// out[n][1024+o]   = sum_{i != n} exp(-sum_k |M[i][o*8+k] - M[n][o*8+k]|)
//
// R13: prep -> gemm_mfma(part) -> reduce (-> TRANSPOSED f16 Mt[o][n][k], *log2e)
//   -> pairwise v12 (coalesced contiguous stage + 1x ds_read_b128 + packed f16).
// R8 profile decomposition: old pairwise = 17.5 us loop + ~13 us scattered
// stage; v12 attacks both.

#define N_ROWS 1024
#define IN_F   1024
#define OUT_C  1056
#define OK     256   // OUT_F*KD
#define KS     8     // K-split factor
#define KC     128   // K-chunk = IN_F/KS
#define LOG2E  1.44269504f

typedef __attribute__((ext_vector_type(8))) short bf16x8;
typedef __attribute__((ext_vector_type(4))) float f32x4;

__device__ __forceinline__ unsigned short f2bf(float f) {
  unsigned u = __float_as_uint(f);
  u = (u + 0x7FFFu + ((u >> 16) & 1u)) >> 16;   // RNE
  return (unsigned short)u;
}

__device__ __forceinline__ float fast_exp2(float x) {
#if __has_builtin(__builtin_amdgcn_exp2f)
  return __builtin_amdgcn_exp2f(x);   // v_exp_f32 = 2^x
#else
  return __expf(x * 0.6931472f);
#endif
}

union HQ { uint4 q; __half2 h[4]; };

// ---------------- kernel 1: prep (R12 verbatim) ------------------------------
__global__ __launch_bounds__(256) void prep_kernel(
    const float* __restrict__ x, const float* __restrict__ T,
    float* __restrict__ out, unsigned short* __restrict__ xb,
    unsigned short* __restrict__ Tt) {
  const int b = blockIdx.x, t = threadIdx.x;
  if (b < 512) {
#pragma unroll
    for (int u = 0; u < 2; ++u) {
      int idx = b * 512 + u * 256 + t;          // 262144 float4 groups
      int row = idx >> 8, col4 = idx & 255;     // rows 2b, 2b+1
      float4 v = *reinterpret_cast<const float4*>(x + (size_t)row * IN_F + col4 * 4);
      *reinterpret_cast<float4*>(out + (size_t)row * OUT_C + col4 * 4) = v;
      ushort4 h = make_ushort4(f2bf(v.x), f2bf(v.y), f2bf(v.z), f2bf(v.w));
      *reinterpret_cast<ushort4*>(xb + (size_t)row * IN_F + col4 * 4) = h;
    }
  } else {
    int c = (b - 512) * 4 + (t >> 6);   // 0..255
    int g = t & 63;
#pragma unroll
    for (int u = 0; u < 2; ++u) {
      int k0 = g * 16 + u * 8;
      unsigned short h[8];
#pragma unroll
      for (int j = 0; j < 8; ++j)
        h[j] = f2bf(T[(size_t)(k0 + j) * OK + c]);
      *reinterpret_cast<uint4*>(Tt + (size_t)c * IN_F + k0) =
          *reinterpret_cast<const uint4*>(h);
    }
  }
}

// ---------------- kernel 2: bf16 MFMA GEMM (R7/R9 verbatim) ------------------
__global__ __launch_bounds__(256) void gemm_mfma_kernel(
    const unsigned short* __restrict__ xb,  // [1024][1024] bf16
    const unsigned short* __restrict__ Tt,  // [256][1024] bf16 (T transposed)
    float* __restrict__ part) {             // [KS][1024][256]
  __shared__ unsigned short asw[64 * 128];
  __shared__ unsigned short bsw[64 * 128];
  const int m0 = blockIdx.x * 64;
  const int n0 = blockIdx.y * 64;
  const int ks = blockIdx.z;
  const int t  = threadIdx.x;

#pragma unroll
  for (int u = 0; u < 4; ++u) {
    int idx = t + 256 * u;
    int row = idx >> 4, slot = idx & 15;
    uint4 va = *reinterpret_cast<const uint4*>(
        xb + (size_t)(m0 + row) * IN_F + ks * KC + slot * 8);
    *reinterpret_cast<uint4*>(asw + row * 128 + ((slot ^ (row & 15)) * 8)) = va;
    uint4 vb = *reinterpret_cast<const uint4*>(
        Tt + (size_t)(n0 + row) * IN_F + ks * KC + slot * 8);
    *reinterpret_cast<uint4*>(bsw + row * 128 + ((slot ^ (row & 15)) * 8)) = vb;
  }
  __syncthreads();

  const int l  = t & 63, w = t >> 6;
  const int lr = l & 15, lg = l >> 4;
  f32x4 acc0 = {0.f, 0.f, 0.f, 0.f};
  f32x4 acc1 = {0.f, 0.f, 0.f, 0.f};
  f32x4 acc2 = {0.f, 0.f, 0.f, 0.f};
  f32x4 acc3 = {0.f, 0.f, 0.f, 0.f};

  const int arow = w * 16 + lr;
  const int aswz = arow & 15;
#pragma unroll
  for (int kk = 0; kk < 4; ++kk) {
    int slotA = kk * 4 + lg;
    bf16x8 a = *reinterpret_cast<const bf16x8*>(
        asw + arow * 128 + ((slotA ^ aswz) * 8));
    int sb = (slotA ^ lr) * 8;
    bf16x8 b0 = *reinterpret_cast<const bf16x8*>(bsw + (lr)      * 128 + sb);
    bf16x8 b1 = *reinterpret_cast<const bf16x8*>(bsw + (16 + lr) * 128 + sb);
    bf16x8 b2 = *reinterpret_cast<const bf16x8*>(bsw + (32 + lr) * 128 + sb);
    bf16x8 b3 = *reinterpret_cast<const bf16x8*>(bsw + (48 + lr) * 128 + sb);
    acc0 = __builtin_amdgcn_mfma_f32_16x16x32_bf16(a, b0, acc0, 0, 0, 0);
    acc1 = __builtin_amdgcn_mfma_f32_16x16x32_bf16(a, b1, acc1, 0, 0, 0);
    acc2 = __builtin_amdgcn_mfma_f32_16x16x32_bf16(a, b2, acc2, 0, 0, 0);
    acc3 = __builtin_amdgcn_mfma_f32_16x16x32_bf16(a, b3, acc3, 0, 0, 0);
  }

  float* dst = part + (size_t)ks * (N_ROWS * OK)
             + (size_t)(m0 + w * 16 + lg * 4) * OK + n0 + lr;
#pragma unroll
  for (int r = 0; r < 4; ++r) {
    dst[(size_t)r * OK]      = acc0[r];
    dst[(size_t)r * OK + 16] = acc1[r];
    dst[(size_t)r * OK + 32] = acc2[r];
    dst[(size_t)r * OK + 48] = acc3[r];
  }
}

// ---------------- kernel 3: reduce partials -> TRANSPOSED f16 Mt -------------
// Mt[o][n][k] = (sum_ks part[ks][n][o*8+k]) * log2e, f16.
// Thread g: n = g>>6, c = (g&63)*4 -> o = c>>3, k = c&7 (k in {0,4}).
__global__ __launch_bounds__(256) void reduce_kernel(
    const float* __restrict__ part, __half* __restrict__ Mt) {
  int g = blockIdx.x * 256 + threadIdx.x;    // 65536 float4 groups
  const float4* p = reinterpret_cast<const float4*>(part);
  float4 s = p[g];
#pragma unroll
  for (int sl = 1; sl < KS; ++sl) {
    float4 v = p[g + (size_t)sl * (N_ROWS * OK / 4)];
    s.x += v.x; s.y += v.y; s.z += v.z; s.w += v.w;
  }
  int n = g >> 6, c = (g & 63) * 4;
  int o = c >> 3, k = c & 7;
  __half2 h01 = __floats2half2_rn(s.x * LOG2E, s.y * LOG2E);
  __half2 h23 = __floats2half2_rn(s.z * LOG2E, s.w * LOG2E);
  uint2 w = make_uint2(*reinterpret_cast<unsigned*>(&h01),
                       *reinterpret_cast<unsigned*>(&h23));
  *reinterpret_cast<uint2*>(Mt + (size_t)o * (N_ROWS * 8) + n * 8 + k) = w;
}

// ---------------- fallback GEMM (small ws): single-pass fp32, scaled ---------
#define BK 16
__global__ __launch_bounds__(256) void gemm32_kernel(
    const float* __restrict__ A, const float* __restrict__ Bm, float* __restrict__ M) {
  __shared__ float as2[BK][32];
  __shared__ float bs2[BK][32];
  int m0 = blockIdx.x * 32;
  int n0 = blockIdx.y * 32;
  int t  = threadIdx.x;
  int ty = t >> 4, tx = t & 15;
  float c00 = 0.f, c01 = 0.f, c10 = 0.f, c11 = 0.f;
  for (int k0 = 0; k0 < IN_F; k0 += BK) {
    if (t < 128) {
      int row = t >> 2, q = t & 3;
      float4 v = *reinterpret_cast<const float4*>(A + (size_t)(m0 + row) * IN_F + k0 + q * 4);
      as2[q * 4 + 0][row] = v.x; as2[q * 4 + 1][row] = v.y;
      as2[q * 4 + 2][row] = v.z; as2[q * 4 + 3][row] = v.w;
    } else {
      int tt = t - 128;
      int row = tt >> 3, q = tt & 7;
      float4 v = *reinterpret_cast<const float4*>(Bm + (size_t)(k0 + row) * OK + n0 + q * 4);
      *reinterpret_cast<float4*>(&bs2[row][q * 4]) = v;
    }
    __syncthreads();
#pragma unroll
    for (int kk = 0; kk < BK; ++kk) {
      float2 a = *reinterpret_cast<const float2*>(&as2[kk][ty * 2]);
      float2 b = *reinterpret_cast<const float2*>(&bs2[kk][tx * 2]);
      c00 += a.x * b.x; c01 += a.x * b.y;
      c10 += a.y * b.x; c11 += a.y * b.y;
    }
    __syncthreads();
  }
  int r = m0 + ty * 2, c = n0 + tx * 2;
  M[(size_t)r * OK + c]           = c00 * LOG2E;
  M[(size_t)r * OK + c + 1]       = c01 * LOG2E;
  M[(size_t)(r + 1) * OK + c]     = c10 * LOG2E;
  M[(size_t)(r + 1) * OK + c + 1] = c11 * LOG2E;
}

// ---------------- kernel 4: pairwise exp2(-L1) v12 ---------------------------
// grid (o:32, jt:16) = 512 blocks x 256 thr (2 blocks/CU, proven shape).
// Stage: CONTIGUOUS 16 KB slice Mt[o] via coalesced uint4 (fixes the ~13 us
// scattered stage). Loop: ONE ds_read_b128 per i + packed-f16 abs-diff tree.
__global__ __launch_bounds__(256) void pairwise12_kernel(
    const __half* __restrict__ Mt, float* __restrict__ out) {
  __shared__ uint4 sm[N_ROWS];      // 16 KB: row n = 8 halves of Mt[o][n][:]
  __shared__ float red[4][64];

  int o  = blockIdx.x;
  int jt = blockIdx.y;
  int t  = threadIdx.x;

  const uint4* src = reinterpret_cast<const uint4*>(Mt + (size_t)o * (N_ROWS * 8));
#pragma unroll
  for (int u = 0; u < 4; ++u)
    sm[t + 256 * u] = src[t + 256 * u];   // fully coalesced, b128 both sides
  __syncthreads();

  int jl = t & 63, s = t >> 6;
  int j  = jt * 64 + jl;

  HQ ju; ju.q = sm[j];
  __half2 r0 = ju.h[0], r1 = ju.h[1], r2 = ju.h[2], r3 = ju.h[3];

  float acc = 0.f;
  const uint4* base = &sm[s * 256];
#pragma unroll 4
  for (int i = 0; i < 256; ++i) {
    HQ u_; u_.q = base[i];              // one ds_read_b128
    __half2 d2 = __hadd2(
        __hadd2(__habs2(__hsub2(u_.h[0], r0)), __habs2(__hsub2(u_.h[1], r1))),
        __hadd2(__habs2(__hsub2(u_.h[2], r2)), __habs2(__hsub2(u_.h[3], r3))));
    float d = __low2float(d2) + __high2float(d2);
    acc += fast_exp2(-d);               // large d underflows to 0
  }
  if ((j >> 8) == s) acc -= 1.0f;       // exact self term exp2(0)=1

  red[s][jl] = acc;
  __syncthreads();

  if (t < 64) {
    float v = red[0][t] + red[1][t] + red[2][t] + red[3][t];
    int jj = jt * 64 + t;
    out[(size_t)jj * OUT_C + 1024 + o] = v;
  }
}

// ---------------- fallback pairwise (f32 M, exp2) + copy ---------------------
__global__ __launch_bounds__(256) void pairwise_kernel(
    const float* __restrict__ M, float* __restrict__ out) {
  __shared__ float sm[N_ROWS][8];
  __shared__ float red[4][64];

  int o  = blockIdx.x;
  int jt = blockIdx.y;
  int t  = threadIdx.x;

#pragma unroll
  for (int idx = t; idx < 2048; idx += 256) {
    int row = idx >> 1, half = idx & 1;
    *reinterpret_cast<float4*>(&sm[row][half * 4]) =
        *reinterpret_cast<const float4*>(M + (size_t)row * OK + o * 8 + half * 4);
  }
  __syncthreads();

  int jl = t & 63, s = t >> 6;
  int j  = jt * 64 + jl;

  float4 ra = *reinterpret_cast<const float4*>(&sm[j][0]);
  float4 rb = *reinterpret_cast<const float4*>(&sm[j][4]);

  float acc = 0.f;
  const float* base = &sm[s * 256][0];
#pragma unroll 4
  for (int i = 0; i < 256; ++i) {
    float4 va = *reinterpret_cast<const float4*>(base + i * 8);
    float4 vb = *reinterpret_cast<const float4*>(base + i * 8 + 4);
    float d = fabsf(va.x - ra.x) + fabsf(va.y - ra.y) +
              fabsf(va.z - ra.z) + fabsf(va.w - ra.w) +
              fabsf(vb.x - rb.x) + fabsf(vb.y - rb.y) +
              fabsf(vb.z - rb.z) + fabsf(vb.w - rb.w);
    acc += fast_exp2(-d);
  }
  if ((j >> 8) == s) acc -= 1.0f;

  red[s][jl] = acc;
  __syncthreads();

  if (t < 64) {
    float v = red[0][t] + red[1][t] + red[2][t] + red[3][t];
    int jj = jt * 64 + t;
    out[(size_t)jj * OUT_C + 1024 + o] = v;
  }
}

__global__ __launch_bounds__(256) void copy_x_kernel(
    const float* __restrict__ x, float* __restrict__ out) {
  int n = blockIdx.x;
  int c = threadIdx.x * 4;
  float4 v = *reinterpret_cast<const float4*>(x + (size_t)n * IN_F + c);
  *reinterpret_cast<float4*>(out + (size_t)n * OUT_C + c) = v;
}

extern "C" void kernel_launch(void* const* d_in, const int* in_sizes, int n_in,
                              void* d_out, int out_size, void* d_ws, size_t ws_size,
                              hipStream_t stream) {
  const float* x = (const float*)d_in[0];   // [1024][1024]
  const float* T = (const float*)d_in[1];   // [1024][256]
  float* out = (float*)d_out;               // [1024][1056]

  const size_t mElems = (size_t)N_ROWS * OK;           // 262144
  const size_t needed = KS * mElems * 4                // part  8 MB
                      + mElems * 2                     // Mt  0.5 MB
                      + (size_t)N_ROWS * IN_F * 2      // xb    2 MB
                      + (size_t)OK * IN_F * 2;         // Tt  0.5 MB

  if (ws_size >= needed) {
    float* part = (float*)d_ws;
    __half* Mt  = (__half*)(part + KS * mElems);
    unsigned short* xb = (unsigned short*)(Mt + mElems);
    unsigned short* Tt = xb + (size_t)N_ROWS * IN_F;

    prep_kernel<<<dim3(576), dim3(256), 0, stream>>>(x, T, out, xb, Tt);
    gemm_mfma_kernel<<<dim3(16, 4, KS), dim3(256), 0, stream>>>(xb, Tt, part);
    reduce_kernel<<<dim3(256), dim3(256), 0, stream>>>(part, Mt);
    pairwise12_kernel<<<dim3(32, 16), dim3(256), 0, stream>>>(Mt, out);
  } else {
    float* M = (float*)d_ws;
    copy_x_kernel<<<dim3(N_ROWS), dim3(256), 0, stream>>>(x, out);
    gemm32_kernel<<<dim3(32, 8), dim3(256), 0, stream>>>(x, T, M);
    pairwise_kernel<<<dim3(32, 16), dim3(256), 0, stream>>>(M, out);
  }
}